// Round 10
// baseline (199.015 us; speedup 1.0000x reference)
//
#include <hip/hip_runtime.h>
#include <stdint.h>

// InstanceHead on MI355X — f32/int32 inputs, f32 OUTPUT buffer.
// N=100000, M=256, B=8, L=128, D=64.
// R15: R14 + ONLINE SOFTMAX (single distance pass).  R14's load batching
// gave the first real win (78->70us): serial-latency chain is the cost.
// Remaining chain: TWO distance passes = 128 ds_read_b128 + ~1400 VALU cy
// (pass1 exists only to find the stabilizer).  R15 keeps a running min m
// and rescaled sum s (flash-style): per mt, m=min(m,d0..d3);
// s=s*exp(m_new-m_old)+sum(exp(m-d)); store e_hat=exp(m-d) packed f16 and
// stab[mt]=m.  Epilogue folds corr=exp(mrow-stab[mt])*sc into the existing
// per-mt scale — the same stab appears in both exps so errors cancel.
// Also: first epilogue cen burst issued BEFORE the pass (pass is DS/VALU
// only -> those 8 dwordx4 fly across it).  Keeps R14: batched ff/wbv
// preloads, transposed GEMM2, dwordx4 stores, geometric batch fold
// (x+=4096*b; cross-batch exp -> exact 0; gate mrow<2000), cmeta LDS,
// wave-private clu_s transpose, __launch_bounds__(256,3).

#define NN 100000
#define MM 256
#define LL 128
#define DD 64
#define NTILES (NN / 16)  // 6250, exact

typedef float f32x4 __attribute__((ext_vector_type(4)));
typedef __bf16 bf16x8 __attribute__((ext_vector_type(8)));
typedef __fp16 fp16x2 __attribute__((ext_vector_type(2)));

union U16x8 { uint4 u; bf16x8 v; unsigned short s[8]; };
union UH2 { unsigned int u; fp16x2 h; };

static __device__ __forceinline__ unsigned short f2bf(float f) {
  union { float f; unsigned int i; } t; t.f = f;
  unsigned int x = t.i;
  x += 0x7fffu + ((x >> 16) & 1u);  // round-to-nearest-even
  return (unsigned short)(x >> 16);
}

// ---------------- prep: cen (bf16), W^T (bf16), centroid meta ----------------
__global__ __launch_bounds__(256) void prep_kernel(
    const int* __restrict__ cen_coords,
    const float* __restrict__ cen_feats,
    const float* __restrict__ conf,
    const float* __restrict__ W,
    const float* __restrict__ bvec,
    unsigned short* __restrict__ cen_ws,   // [256][64] bf16
    unsigned short* __restrict__ wt_ws,    // [64][128] bf16 (W transposed)
    float4* __restrict__ cmeta_ws)         // [256] {x+4096*batch, y, z, 0}
{
  int tid = threadIdx.x;
  if (blockIdx.x < 16) {
    int m = blockIdx.x * 16 + (tid >> 4);
    int c = tid & 15;
    float a0 = 0.f, a1 = 0.f, a2 = 0.f, a3 = 0.f;
    for (int l = 0; l < LL; l++) {
      float f = cen_feats[m * LL + l];
      const float* wr = W + l * DD + c;
      a0 += f * wr[0];  a1 += f * wr[16];
      a2 += f * wr[32]; a3 += f * wr[48];
    }
    float cf = conf[m];
    cen_ws[m * DD + c +  0] = f2bf(cf * (a0 + bvec[c +  0]));
    cen_ws[m * DD + c + 16] = f2bf(cf * (a1 + bvec[c + 16]));
    cen_ws[m * DD + c + 32] = f2bf(cf * (a2 + bvec[c + 32]));
    cen_ws[m * DD + c + 48] = f2bf(cf * (a3 + bvec[c + 48]));
  } else {
    for (int i = tid; i < LL * DD; i += 256) {
      int l = i >> 6, d = i & 63;
      wt_ws[d * LL + l] = f2bf(W[l * DD + d]);
    }
    {
      int4 cc = ((const int4*)cen_coords)[tid];  // {batch, x, y, z}
      float4 f;
      f.x = (float)cc.y + 4096.0f * (float)cc.x;  // batch folded into x
      f.y = (float)cc.z;
      f.z = (float)cc.w;
      f.w = 0.0f;
      cmeta_ws[tid] = f;
    }
  }
}

// ---------------- main: fused, 1 wave/tile, online-softmax version ----------------
__global__ __launch_bounds__(256, 3) void main_kernel(
    const int4* __restrict__ clu_coords4,
    const float* __restrict__ feats,
    const float* __restrict__ bvec,
    const unsigned short* __restrict__ cen_ws,
    const unsigned short* __restrict__ wt_ws,
    const float4* __restrict__ cmeta,
    float* __restrict__ out)
{
  __shared__ __align__(16) unsigned short clu_s[4][16 * 72];  // wave-private
  __shared__ __align__(16) float4 cmeta_s[MM];                // block-shared

  int tid = threadIdx.x;
  cmeta_s[tid] = cmeta[tid];   // stage once per block
  __syncthreads();             // before any divergent exit

  int wave = tid >> 6, lane = tid & 63;
  int q = lane >> 4, c = lane & 15;
  int tile = blockIdx.x * 4 + wave;
  if (tile >= NTILES) return;

  // ---- batched long-latency loads: feats (8x dwordx4), W frags (16x dwordx4),
  //      row coord — ALL issued before any dependent compute.
  const float4* fb = (const float4*)(feats + (size_t)(tile * 16 + c) * LL);
  float4 ff[8];
#pragma unroll
  for (int ks = 0; ks < 4; ks++) {
    ff[2 * ks]     = fb[ks * 8 + q * 2];
    ff[2 * ks + 1] = fb[ks * 8 + q * 2 + 1];
  }
  const uint4* wb = (const uint4*)wt_ws;
  uint4 wbv[16];
#pragma unroll
  for (int ks = 0; ks < 4; ks++)
#pragma unroll
    for (int nt = 0; nt < 4; nt++)
      wbv[ks * 4 + nt] = wb[(nt * 16 + c) * 16 + ks * 4 + q];
  int4 rm = clu_coords4[tile * 16 + c];  // one row per lane (4-way broadcast)
  float rx = (float)rm.y + 4096.0f * (float)rm.x;  // batch folded, exact
  float ry = (float)rm.z;
  float rz = (float)rm.w;

  // ---- GEMM1: clu = feats @ W (+b)
  f32x4 acc[4] = {{0,0,0,0},{0,0,0,0},{0,0,0,0},{0,0,0,0}};
#pragma unroll
  for (int ks = 0; ks < 4; ks++) {
    float4 f0 = ff[2 * ks], f1 = ff[2 * ks + 1];
    U16x8 a;
    a.v[0] = (__bf16)f0.x; a.v[1] = (__bf16)f0.y; a.v[2] = (__bf16)f0.z; a.v[3] = (__bf16)f0.w;
    a.v[4] = (__bf16)f1.x; a.v[5] = (__bf16)f1.y; a.v[6] = (__bf16)f1.z; a.v[7] = (__bf16)f1.w;
#pragma unroll
    for (int nt = 0; nt < 4; nt++) {
      U16x8 b; b.u = wbv[ks * 4 + nt];
      acc[nt] = __builtin_amdgcn_mfma_f32_16x16x32_bf16(a.v, b.v, acc[nt], 0, 0, 0);
    }
  }
#pragma unroll
  for (int nt = 0; nt < 4; nt++) {
    float bv = bvec[nt * 16 + c];
    acc[nt][0] += bv; acc[nt][1] += bv; acc[nt][2] += bv; acc[nt][3] += bv;
  }
  // ---- row L2 norms (GEMM1 fragment rows q*4+r live across quad q's lanes)
  float inv_nrm[4];
#pragma unroll
  for (int r = 0; r < 4; r++) {
    float s = acc[0][r]*acc[0][r] + acc[1][r]*acc[1][r] + acc[2][r]*acc[2][r] + acc[3][r]*acc[3][r];
    s += __shfl_xor(s, 1); s += __shfl_xor(s, 2); s += __shfl_xor(s, 4); s += __shfl_xor(s, 8);
    inv_nrm[r] = 1.0f / fmaxf(sqrtf(s), 1e-12f);
  }
  // normalized clu -> LDS (bf16); inv_nrm applied HERE only
#pragma unroll
  for (int nt = 0; nt < 4; nt++)
#pragma unroll
    for (int r = 0; r < 4; r++) {
      union { __bf16 h; unsigned short s; } u;
      u.h = (__bf16)(acc[nt][r] * inv_nrm[r]);
      clu_s[wave][(q * 4 + r) * 72 + nt * 16 + c] = u.s;
    }

  // wave-private LDS transpose: DS pipe is in-order per wave, no barrier
  __builtin_amdgcn_sched_barrier(0);

  // ---- clu frags (B-operand of the swapped GEMM2): row c, k-slice q
  const uint4* cb = (const uint4*)(clu_s[wave]);
  U16x8 a0, a1;
  a0.u = cb[c * 9 + q];       // k = q*8 .. q*8+7
  a1.u = cb[c * 9 + 4 + q];   // k = 32+q*8 ..

  // ---- issue the FIRST epilogue cen burst now; the distance pass below is
  //      DS/VALU-only, so these 8 dwordx4 stay in flight across it.
  const uint4* cenb = (const uint4*)cen_ws;
  uint4 pb0[4], pb1[4];
#pragma unroll
  for (int j = 0; j < 4; j++) {
    pb0[j] = cenb[(j * 16 + c) * 8 + q];
    pb1[j] = cenb[(j * 16 + c) * 8 + 4 + q];
  }

  // ---- ONE distance pass, online softmax (running min m, rescaled sum s)
  //      element (row c, col mt*16+q*4+r); cross-batch d>=3073 -> exp=0
  float m = 1e30f, s = 0.f;
  float stab[16];
  uint2 ep[16];
#pragma unroll
  for (int mt = 0; mt < 16; mt++) {
    float4 cm0 = cmeta_s[mt * 16 + q * 4 + 0];
    float4 cm1 = cmeta_s[mt * 16 + q * 4 + 1];
    float4 cm2 = cmeta_s[mt * 16 + q * 4 + 2];
    float4 cm3 = cmeta_s[mt * 16 + q * 4 + 3];
    float dx, dy, dz;
    dx = rx - cm0.x; dy = ry - cm0.y; dz = rz - cm0.z;
    float d0 = fmaxf(sqrtf(dx*dx + dy*dy + dz*dz), 0.1f);
    dx = rx - cm1.x; dy = ry - cm1.y; dz = rz - cm1.z;
    float d1 = fmaxf(sqrtf(dx*dx + dy*dy + dz*dz), 0.1f);
    dx = rx - cm2.x; dy = ry - cm2.y; dz = rz - cm2.z;
    float d2 = fmaxf(sqrtf(dx*dx + dy*dy + dz*dz), 0.1f);
    dx = rx - cm3.x; dy = ry - cm3.y; dz = rz - cm3.z;
    float d3 = fmaxf(sqrtf(dx*dx + dy*dy + dz*dz), 0.1f);
    float mnew = fminf(fminf(fminf(fminf(m, d0), d1), d2), d3);
    s *= __expf(mnew - m);          // branchless rescale (<=1; exp(0)=1)
    m = mnew;
    float e0 = __expf(m - d0);      // all <= 1 (m includes this group)
    float e1 = __expf(m - d1);
    float e2 = __expf(m - d2);
    float e3 = __expf(m - d3);
    s += (e0 + e1) + (e2 + e3);
    stab[mt] = m;
    UH2 p0, p1;
    p0.h = __builtin_amdgcn_cvt_pkrtz(e0, e1);
    p1.h = __builtin_amdgcn_cvt_pkrtz(e2, e3);
    ep[mt].x = p0.u;
    ep[mt].y = p1.u;
  }
  // row-level combine over the 4 q-lanes (same c): min and rescaled sum
  float mrow = fminf(m, __shfl_xor(m, 16));
  mrow = fminf(mrow, __shfl_xor(mrow, 32));
  float sadj = s * __expf(mrow - m);
  sadj += __shfl_xor(sadj, 16);
  sadj += __shfl_xor(sadj, 32);
  // mrow >= 2000 <=> no same-batch centroid (cross-batch min >= 3073)
  float sc = (mrow < 2000.0f) ? 1.0f / sadj : 0.f;

  // ---- epilogue: swapped GEMM2, 4-deep pipelined cen prefetch;
  //      per-mt corr = exp(mrow - stab[mt]) * sc folds the stabilizer fix.
  float4* ob4 = (float4*)(out + (size_t)(tile * 16 + c) * MM) + q;
#pragma unroll
  for (int g = 0; g < 4; g++) {
    uint4 nb0[4], nb1[4];
    if (g < 3) {
#pragma unroll
      for (int j = 0; j < 4; j++) {
        nb0[j] = cenb[(((g + 1) * 4 + j) * 16 + c) * 8 + q];
        nb1[j] = cenb[(((g + 1) * 4 + j) * 16 + c) * 8 + 4 + q];
      }
    }
#pragma unroll
    for (int j = 0; j < 4; j++) {
      int mt = g * 4 + j;
      U16x8 b0, b1; b0.u = pb0[j]; b1.u = pb1[j];
      f32x4 dacc = {0, 0, 0, 0};
      dacc = __builtin_amdgcn_mfma_f32_16x16x32_bf16(b0.v, a0.v, dacc, 0, 0, 0);  // SWAPPED
      dacc = __builtin_amdgcn_mfma_f32_16x16x32_bf16(b1.v, a1.v, dacc, 0, 0, 0);
      float f = __expf(mrow - stab[mt]) * sc;
      UH2 p0, p1; p0.u = ep[mt].x; p1.u = ep[mt].y;
      float4 v;
      v.x = dacc[0] * ((float)p0.h[0] * f);
      v.y = dacc[1] * ((float)p0.h[1] * f);
      v.z = dacc[2] * ((float)p1.h[0] * f);
      v.w = dacc[3] * ((float)p1.h[1] * f);
      ob4[mt * 4] = v;   // imm offset mt*64B, one base per lane
    }
    if (g < 3) {
#pragma unroll
      for (int j = 0; j < 4; j++) { pb0[j] = nb0[j]; pb1[j] = nb1[j]; }
    }
  }
}

extern "C" void kernel_launch(void* const* d_in, const int* in_sizes, int n_in,
                              void* d_out, int out_size, void* d_ws, size_t ws_size,
                              hipStream_t stream) {
  const int* clu_coords = (const int*)d_in[0];
  const int* cen_coords = (const int*)d_in[1];
  const float* clu_feats = (const float*)d_in[2];
  const float* cen_feats = (const float*)d_in[3];
  const float* conf      = (const float*)d_in[4];
  const float* W         = (const float*)d_in[5];
  const float* bvec      = (const float*)d_in[6];
  float* out = (float*)d_out;

  char* ws = (char*)d_ws;
  unsigned short* cen_ws = (unsigned short*)ws;              // 32768 B
  unsigned short* wt_ws  = (unsigned short*)(ws + 32768);    // 16384 B
  float4* cmeta_ws       = (float4*)(ws + 32768 + 16384);    // 4096 B

  prep_kernel<<<17, 256, 0, stream>>>(cen_coords, cen_feats, conf, W, bvec,
                                      cen_ws, wt_ws, cmeta_ws);
  main_kernel<<<(NTILES + 3) / 4, 256, 0, stream>>>(
      (const int4*)clu_coords, clu_feats, bvec, cen_ws, wt_ws, cmeta_ws, out);
}